// Round 4
// baseline (198.290 us; speedup 1.0000x reference)
//
#include <hip/hip_runtime.h>
#include <hip/hip_bf16.h>
#include <math.h>

#define BATCH 8
#define SEQ   2048
#define EMB   1024
#define HEAD  64
#define BT    (BATCH * SEQ)

typedef __attribute__((ext_vector_type(8))) short  short8;
typedef __attribute__((ext_vector_type(4))) float  floatx4;

__device__ __forceinline__ unsigned short f2bf(float x) {
    union { __hip_bfloat16 h; unsigned short u; } cv;
    cv.h = __float2bfloat16(x);   // RNE
    return cv.u;
}

// =====================================================================
// Kernel 0: transpose+convert weights -> WT[192][1024] bf16.
// WT[c][k]: c in [0,64)=Wq col, [64,128)=Wk, [128,192)=Wv.
// =====================================================================
__global__ __launch_bounds__(256) void wt_prep(
    const float* __restrict__ Wq, const float* __restrict__ Wk,
    const float* __restrict__ Wv, unsigned short* __restrict__ WT)
{
    __shared__ float tile[64][65];
    const int w  = blockIdx.x >> 4;        // 0..2
    const int k0 = (blockIdx.x & 15) * 64;
    const float* W = (w == 0) ? Wq : (w == 1) ? Wk : Wv;
    const int tid = threadIdx.x;

    for (int idx = tid; idx < 4096; idx += 256) {
        const int kr = idx >> 6, n = idx & 63;       // coalesced over n
        tile[kr][n] = W[(size_t)(k0 + kr) * HEAD + n];
    }
    __syncthreads();
    const int n  = tid >> 2;
    const int k8 = (tid & 3) * 16;
    unsigned short* dst = WT + (size_t)(w * 64 + n) * EMB + k0 + k8;
    short8 v0, v1;
#pragma unroll
    for (int j = 0; j < 8; ++j) v0[j] = (short)f2bf(tile[k8 + j][n]);
#pragma unroll
    for (int j = 0; j < 8; ++j) v1[j] = (short)f2bf(tile[k8 + 8 + j][n]);
    *(short8*)(dst)     = v0;
    *(short8*)(dst + 8) = v1;
}

// =====================================================================
// Kernel 1: QKV projection via bf16 MFMA 16x16x32, 2-stage reg pipeline.
// grid = BT/16 = 1024 blocks x 256 thr (4 waves).
// Wave wv: rows blockIdx*16..+15, cols wv*48..+47 (3 n-tiles).
// All 4 waves share the same X rows (L1 hits after first wave).
// Outputs: Q,K natural [t][64] bf16; V transposed VT[b][64][2048] bf16.
// =====================================================================
__global__ __launch_bounds__(256) void qkv_mfma(
    const float* __restrict__ X, const unsigned short* __restrict__ WT,
    unsigned short* __restrict__ Q, unsigned short* __restrict__ K,
    unsigned short* __restrict__ VT)
{
    const int tid = threadIdx.x;
    const int l   = tid & 63;
    const int wv  = tid >> 6;              // 0..3
    const int g   = l >> 4,  q  = l & 15;
    const int arow = blockIdx.x * 16 + q;

    floatx4 acc[3];
#pragma unroll
    for (int nt = 0; nt < 3; ++nt) acc[nt] = (floatx4){0.f, 0.f, 0.f, 0.f};

    const float*          xp = X  + (size_t)arow * EMB + g * 8;
    const unsigned short* wp = WT + (size_t)(wv * 48 + q) * EMB + g * 8;

    // prologue: load chunk 0
    float4 xa = *(const float4*)(xp);
    float4 xb = *(const float4*)(xp + 4);
    short8 w[3];
#pragma unroll
    for (int nt = 0; nt < 3; ++nt) w[nt] = *(const short8*)(wp + (size_t)nt * 16 * EMB);

    for (int k0 = 0; k0 < EMB - 32; k0 += 32) {
        // issue next-chunk loads (latency hides under compute below)
        float4 xa2 = *(const float4*)(xp + 32);
        float4 xb2 = *(const float4*)(xp + 36);
        short8 w2[3];
#pragma unroll
        for (int nt = 0; nt < 3; ++nt) w2[nt] = *(const short8*)(wp + 32 + (size_t)nt * 16 * EMB);
        xp += 32; wp += 32;

        short8 a;
        a[0] = (short)f2bf(xa.x); a[1] = (short)f2bf(xa.y);
        a[2] = (short)f2bf(xa.z); a[3] = (short)f2bf(xa.w);
        a[4] = (short)f2bf(xb.x); a[5] = (short)f2bf(xb.y);
        a[6] = (short)f2bf(xb.z); a[7] = (short)f2bf(xb.w);
#pragma unroll
        for (int nt = 0; nt < 3; ++nt)
            acc[nt] = __builtin_amdgcn_mfma_f32_16x16x32_bf16(a, w[nt], acc[nt], 0, 0, 0);

        xa = xa2; xb = xb2;
#pragma unroll
        for (int nt = 0; nt < 3; ++nt) w[nt] = w2[nt];
    }
    {   // final chunk
        short8 a;
        a[0] = (short)f2bf(xa.x); a[1] = (short)f2bf(xa.y);
        a[2] = (short)f2bf(xa.z); a[3] = (short)f2bf(xa.w);
        a[4] = (short)f2bf(xb.x); a[5] = (short)f2bf(xb.y);
        a[6] = (short)f2bf(xb.z); a[7] = (short)f2bf(xb.w);
#pragma unroll
        for (int nt = 0; nt < 3; ++nt)
            acc[nt] = __builtin_amdgcn_mfma_f32_16x16x32_bf16(a, w[nt], acc[nt], 0, 0, 0);
    }

    // C/D layout: col = lane&15 (=q), row = (lane>>4)*4 + r.
    const int trow0 = blockIdx.x * 16 + g * 4;
#pragma unroll
    for (int nt = 0; nt < 3; ++nt) {
        const int c = wv * 48 + nt * 16 + q;
#pragma unroll
        for (int r = 0; r < 4; ++r) {
            const unsigned short v = f2bf(acc[nt][r]);
            const int t = trow0 + r;
            if (c < 64) {
                Q[(size_t)t * HEAD + c] = v;
            } else if (c < 128) {
                K[(size_t)t * HEAD + (c - 64)] = v;
            } else {
                const int bb = t >> 11, tl = t & (SEQ - 1);
                VT[((size_t)bb * HEAD + (c - 128)) * SEQ + tl] = v;
            }
        }
    }
}

// =====================================================================
// Kernel 2: causal flash attention via bf16 MFMA, pipelined + split-KV.
// grid = 64 q-tiles x 8 batches = 512 blocks x 256 thr (4 waves).
// Waves 0,1 (pair 0) own rows qt*32+{0..15},{16..31} for EVEN kv tiles;
// waves 2,3 (pair 1) same rows for ODD kv tiles. KV staging/barriers
// shared by all 4 waves; softmax states merged via LDS at the end.
// Double-buffered K/V LDS; prefetch issued after the barrier.
// =====================================================================
__global__ __launch_bounds__(256) void attn_mfma(
    const unsigned short* __restrict__ Q, const unsigned short* __restrict__ K,
    const unsigned short* __restrict__ VT, float* __restrict__ O)
{
    __shared__ unsigned short Ks[2][64][72];   // [buf][kk][d]
    __shared__ unsigned short Vs[2][64][72];   // [buf][d][kk]
    __shared__ unsigned short Ps[64][72];      // [wv*16+q][kk]
    __shared__ float Mo[2][16][68];            // merge: pair-1 O partial
    __shared__ float Mm[2][16], Ml[2][16];     // merge: pair-1 m,l

    const int tid  = threadIdx.x;
    const int l    = tid & 63;
    const int wv   = tid >> 6;               // 0..3
    const int pair = wv >> 1, sub = wv & 1;
    const int g    = l >> 4, q = l & 15;
    const int qt   = 63 - (blockIdx.x >> 3); // largest-work blocks first
    const int b    = blockIdx.x & 7;
    const int qrow0 = qt * 32 + sub * 16;
    const size_t kbase = (size_t)b * SEQ * HEAD;
    const size_t vbase = (size_t)b * HEAD * SEQ;

    // Q^T B-frags: col=q, k=d=(dc*32 + g*8 + j). Held in regs for all tiles.
    short8 bq[2];
#pragma unroll
    for (int dc = 0; dc < 2; ++dc)
        bq[dc] = *(const short8*)&Q[kbase + (size_t)(qrow0 + q) * HEAD + dc * 32 + g * 8];

    floatx4 o[4];
#pragma unroll
    for (int dt = 0; dt < 4; ++dt) o[dt] = (floatx4){0.f, 0.f, 0.f, 0.f};
    float m_run = -INFINITY, l_run = 0.f;

    const int nkt = (qt >> 1) + 1;

    // prologue: prefetch tile 0 into regs (2 short8 K + 2 short8 V per thr)
    short8 kreg[2], vreg[2];
#pragma unroll
    for (int i = 0; i < 2; ++i) {
        const int c = tid + i * 256, r = c >> 3, k8 = (c & 7) * 8;
        kreg[i] = *(const short8*)&K [kbase + (size_t)r * HEAD + k8];
        vreg[i] = *(const short8*)&VT[vbase + (size_t)r * SEQ  + k8];
    }

    for (int kt = 0; kt < nkt; ++kt) {
        const int bs = kt & 1;
        // stage prefetched regs -> LDS (compiler inserts vmcnt wait here)
#pragma unroll
        for (int i = 0; i < 2; ++i) {
            const int c = tid + i * 256, r = c >> 3, k8 = (c & 7) * 8;
            *(short8*)&Ks[bs][r][k8] = kreg[i];
            *(short8*)&Vs[bs][r][k8] = vreg[i];
        }
        __syncthreads();

        // issue next-tile loads; latency hides under compute below
        if (kt + 1 < nkt) {
#pragma unroll
            for (int i = 0; i < 2; ++i) {
                const int c = tid + i * 256, r = c >> 3, k8 = (c & 7) * 8;
                kreg[i] = *(const short8*)&K [kbase + (size_t)((kt + 1) * 64 + r) * HEAD + k8];
                vreg[i] = *(const short8*)&VT[vbase + (size_t)r * SEQ + (kt + 1) * 64 + k8];
            }
        }

        if ((kt & 1) == pair) {
            // ---- S^T: 4 kk-tiles x 2 d-chunks ----
            floatx4 s[4];
#pragma unroll
            for (int t = 0; t < 4; ++t) {
                s[t] = (floatx4){0.f, 0.f, 0.f, 0.f};
#pragma unroll
                for (int dc = 0; dc < 2; ++dc) {
                    const short8 ak = *(const short8*)&Ks[bs][t * 16 + q][dc * 32 + g * 8];
                    s[t] = __builtin_amdgcn_mfma_f32_16x16x32_bf16(ak, bq[dc], s[t], 0, 0, 0);
                }
            }

            // ---- scale + causal mask (diag tile only) ----
            float sv[4][4];
            if (kt == nkt - 1) {
#pragma unroll
                for (int t = 0; t < 4; ++t)
#pragma unroll
                    for (int r = 0; r < 4; ++r) {
                        const int kg = kt * 64 + t * 16 + g * 4 + r;
                        sv[t][r] = (kg > qrow0 + q) ? -INFINITY : s[t][r] * 0.125f;
                    }
            } else {
#pragma unroll
                for (int t = 0; t < 4; ++t)
#pragma unroll
                    for (int r = 0; r < 4; ++r) sv[t][r] = s[t][r] * 0.125f;
            }

            // ---- online softmax (row = q, spread over 4 g-lanes) ----
            float pm = -INFINITY;
#pragma unroll
            for (int t = 0; t < 4; ++t)
#pragma unroll
                for (int r = 0; r < 4; ++r) pm = fmaxf(pm, sv[t][r]);
            pm = fmaxf(pm, __shfl_xor(pm, 16));
            pm = fmaxf(pm, __shfl_xor(pm, 32));
            const float mnew = fmaxf(m_run, pm);
            const float crow = __expf(m_run - mnew);   // first tile: exp(-inf)=0
            float p[4][4];
            float psum = 0.f;
#pragma unroll
            for (int t = 0; t < 4; ++t)
#pragma unroll
                for (int r = 0; r < 4; ++r) {
                    p[t][r] = __expf(sv[t][r] - mnew);
                    psum += p[t][r];
                }
            psum += __shfl_xor(psum, 16);
            psum += __shfl_xor(psum, 32);
            l_run = l_run * crow + psum;
            m_run = mnew;

            // rescale O: lane holds O rows q' = g*4+r; fetch crow from lane q'.
#pragma unroll
            for (int r = 0; r < 4; ++r) {
                const float cr = __shfl(crow, g * 4 + r);
#pragma unroll
                for (int dt = 0; dt < 4; ++dt) o[dt][r] *= cr;
            }

            // ---- P -> LDS (bf16, packed pairs) ----
#pragma unroll
            for (int t = 0; t < 4; ++t) {
                const unsigned int lo = (unsigned)f2bf(p[t][0]) | ((unsigned)f2bf(p[t][1]) << 16);
                const unsigned int hi = (unsigned)f2bf(p[t][2]) | ((unsigned)f2bf(p[t][3]) << 16);
                *(unsigned int*)&Ps[wv * 16 + q][t * 16 + g * 4]     = lo;
                *(unsigned int*)&Ps[wv * 16 + q][t * 16 + g * 4 + 2] = hi;
            }
            // wave-local write->read fence (cross-lane via LDS, same wave)
            asm volatile("s_waitcnt lgkmcnt(0)" ::: "memory");
            __builtin_amdgcn_sched_barrier(0);

            // ---- PV: O[q][d] += P[q][kk] * V[kk][d] ----
#pragma unroll
            for (int kc = 0; kc < 2; ++kc) {
                const short8 pa = *(const short8*)&Ps[wv * 16 + q][kc * 32 + g * 8];
#pragma unroll
                for (int dt = 0; dt < 4; ++dt) {
                    const short8 vb = *(const short8*)&Vs[bs][dt * 16 + q][kc * 32 + g * 8];
                    o[dt] = __builtin_amdgcn_mfma_f32_16x16x32_bf16(pa, vb, o[dt], 0, 0, 0);
                }
            }
        }
    }

    // ---- merge pair-1 state into pair-0, normalize, store fp32 ----
    __syncthreads();
    if (pair == 1) {
#pragma unroll
        for (int dt = 0; dt < 4; ++dt)
#pragma unroll
            for (int r = 0; r < 4; ++r)
                Mo[sub][g * 4 + r][dt * 16 + q] = o[dt][r];
        if (g == 0) { Mm[sub][q] = m_run; Ml[sub][q] = l_run; }
    }
    __syncthreads();
    if (pair == 0) {
        const float m1  = Mm[sub][q];
        const float l1v = Ml[sub][q];
        const float mx  = fmaxf(m_run, m1);
        const float c0  = __expf(m_run - mx);
        const float c1  = __expf(m1 - mx);     // m1=-inf (no odd tiles) -> 0
        const float lm  = l_run * c0 + l1v * c1;
        const size_t obase = (size_t)b * SEQ * HEAD;
#pragma unroll
        for (int r = 0; r < 4; ++r) {
            const float c0r = __shfl(c0, g * 4 + r);
            const float c1r = __shfl(c1, g * 4 + r);
            const float lr  = __shfl(lm, g * 4 + r);
            const float inv = 1.0f / lr;
#pragma unroll
            for (int dt = 0; dt < 4; ++dt) {
                const float val = o[dt][r] * c0r + Mo[sub][g * 4 + r][dt * 16 + q] * c1r;
                O[obase + (size_t)(qrow0 + g * 4 + r) * HEAD + dt * 16 + q] = val * inv;
            }
        }
    }
}

// =====================================================================
extern "C" void kernel_launch(void* const* d_in, const int* in_sizes, int n_in,
                              void* d_out, int out_size, void* d_ws, size_t ws_size,
                              hipStream_t stream)
{
    const float* X  = (const float*)d_in[0];
    const float* Wq = (const float*)d_in[1];
    const float* Wk = (const float*)d_in[2];
    const float* Wv = (const float*)d_in[3];
    float* O = (float*)d_out;

    unsigned short* Qb = (unsigned short*)d_ws;              // [BT][64] bf16
    unsigned short* Kb = Qb + (size_t)BT * HEAD;             // [BT][64]
    unsigned short* Vt = Kb + (size_t)BT * HEAD;             // [B][64][2048]
    unsigned short* WT = Vt + (size_t)BT * HEAD;             // [192][1024]

    wt_prep  <<<dim3(48),   dim3(256), 0, stream>>>(Wq, Wk, Wv, WT);
    qkv_mfma <<<dim3(1024), dim3(256), 0, stream>>>(X, WT, Qb, Kb, Vt);
    attn_mfma<<<dim3(512),  dim3(256), 0, stream>>>(Qb, Kb, Vt, O);
}

// Round 5
// 173.634 us; speedup vs baseline: 1.1420x; 1.1420x over previous
//
#include <hip/hip_runtime.h>
#include <hip/hip_bf16.h>
#include <math.h>

#define BATCH 8
#define SEQ   2048
#define EMB   1024
#define HEAD  64
#define BT    (BATCH * SEQ)

typedef __attribute__((ext_vector_type(8))) short  short8;
typedef __attribute__((ext_vector_type(4))) float  floatx4;

__device__ __forceinline__ unsigned short f2bf(float x) {
    union { __hip_bfloat16 h; unsigned short u; } cv;
    cv.h = __float2bfloat16(x);   // RNE
    return cv.u;
}

// =====================================================================
// Kernel 0: transpose+convert weights -> WT[192][1024] bf16.
// WT[c][k]: c in [0,64)=Wq col, [64,128)=Wk, [128,192)=Wv.
// =====================================================================
__global__ __launch_bounds__(256) void wt_prep(
    const float* __restrict__ Wq, const float* __restrict__ Wk,
    const float* __restrict__ Wv, unsigned short* __restrict__ WT)
{
    __shared__ float tile[64][65];
    const int w  = blockIdx.x >> 4;        // 0..2
    const int k0 = (blockIdx.x & 15) * 64;
    const float* W = (w == 0) ? Wq : (w == 1) ? Wk : Wv;
    const int tid = threadIdx.x;

    for (int idx = tid; idx < 4096; idx += 256) {
        const int kr = idx >> 6, n = idx & 63;       // coalesced over n
        tile[kr][n] = W[(size_t)(k0 + kr) * HEAD + n];
    }
    __syncthreads();
    const int n  = tid >> 2;
    const int k8 = (tid & 3) * 16;
    unsigned short* dst = WT + (size_t)(w * 64 + n) * EMB + k0 + k8;
    short8 v0, v1;
#pragma unroll
    for (int j = 0; j < 8; ++j) v0[j] = (short)f2bf(tile[k8 + j][n]);
#pragma unroll
    for (int j = 0; j < 8; ++j) v1[j] = (short)f2bf(tile[k8 + 8 + j][n]);
    *(short8*)(dst)     = v0;
    *(short8*)(dst + 8) = v1;
}

// =====================================================================
// Kernel 1: QKV projection as 2-phase LDS-staged GEMM.
// grid = BT/32 = 512 blocks x 512 thr (8 waves = 2M x 4N).
// Block: 32 rows x 192 cols, K in 16 chunks of 64.
// X fp32 -> double-buffered LDS [2][32][64], XOR-swizzled (row&7)<<5
// on both ds_write and ds_read (T2); global source stays linear
// (reg-staged). W per-wave register prefetch, parity-indexed.
// Loads for chunk t+1 issued at phase top; ds_write after barrier (T14).
// Outputs: Q,K natural [t][64] bf16; V transposed VT[b][64][2048] bf16.
// =====================================================================
__global__ __launch_bounds__(512) void qkv_mfma(
    const float* __restrict__ X, const unsigned short* __restrict__ WT,
    unsigned short* __restrict__ Q, unsigned short* __restrict__ K,
    unsigned short* __restrict__ VT)
{
    __shared__ float Xs[2][32 * 64];       // 16 KB total, swizzled layout

    const int tid = threadIdx.x;
    const int l   = tid & 63;
    const int wv  = tid >> 6;              // 0..7
    const int wm  = wv >> 2, wn = wv & 3;  // 2M x 4N
    const int g   = l >> 4,  q  = l & 15;
    const int row0 = blockIdx.x * 32;

    // staging coords: 512 thr x 1 float4 = 32 rows x 64 k fp32
    const int sr = tid >> 4, sj = tid & 15;
    const float* xsrc = X + (size_t)(row0 + sr) * EMB + sj * 4;
    const int soff = sr * 256 + ((sj * 16) ^ ((sr & 7) << 5));
    char* const sdst0 = (char*)&Xs[0][0] + soff;
    char* const sdst1 = (char*)&Xs[1][0] + soff;

    const unsigned short* wbase = WT + (size_t)(wn * 48 + q) * EMB + g * 8;

    floatx4 acc[3];
#pragma unroll
    for (int nt = 0; nt < 3; ++nt) acc[nt] = (floatx4){0.f, 0.f, 0.f, 0.f};

    short8 wreg[2][6];
    float4 xreg;

    // prologue: chunk 0
    xreg = *(const float4*)(xsrc);
#pragma unroll
    for (int nt = 0; nt < 3; ++nt)
#pragma unroll
        for (int kc = 0; kc < 2; ++kc)
            wreg[0][nt * 2 + kc] = *(const short8*)(wbase + (size_t)nt * 16 * EMB + kc * 32);
    *(float4*)sdst0 = xreg;
    __syncthreads();

    // A-frag read coords
    const int rr = wm * 16 + q;
    const int sw = (rr & 7) << 5;
    const char* const abase0 = (const char*)&Xs[0][0] + rr * 256;
    const char* const abase1 = (const char*)&Xs[1][0] + rr * 256;

#pragma unroll
    for (int t = 0; t < 16; ++t) {
        const int cur = t & 1, nxt = cur ^ 1;
        // issue next-chunk loads (latency hides under compute below)
        if (t + 1 < 16) {
            xreg = *(const float4*)(xsrc + (t + 1) * 64);
#pragma unroll
            for (int nt = 0; nt < 3; ++nt)
#pragma unroll
                for (int kc = 0; kc < 2; ++kc)
                    wreg[nxt][nt * 2 + kc] =
                        *(const short8*)(wbase + (size_t)nt * 16 * EMB + (t + 1) * 64 + kc * 32);
        }
        // compute chunk t from LDS buf(cur)
        const char* abase = cur ? abase1 : abase0;
#pragma unroll
        for (int kc = 0; kc < 2; ++kc) {
            const int koff = (kc * 128 + g * 32) ^ sw;
            const float4 xa = *(const float4*)(abase + koff);
            const float4 xb = *(const float4*)(abase + koff + 16);   // +16 flips bit4 only; sw uses bits 5..7
            short8 a;
            a[0] = (short)f2bf(xa.x); a[1] = (short)f2bf(xa.y);
            a[2] = (short)f2bf(xa.z); a[3] = (short)f2bf(xa.w);
            a[4] = (short)f2bf(xb.x); a[5] = (short)f2bf(xb.y);
            a[6] = (short)f2bf(xb.z); a[7] = (short)f2bf(xb.w);
#pragma unroll
            for (int nt = 0; nt < 3; ++nt)
                acc[nt] = __builtin_amdgcn_mfma_f32_16x16x32_bf16(a, wreg[cur][nt * 2 + kc], acc[nt], 0, 0, 0);
        }
        if (t + 1 < 16) {
            __syncthreads();                       // all waves done reading buf(nxt)'s old tile
            *(float4*)(nxt ? sdst1 : sdst0) = xreg; // vmcnt wait via reg dep
            __syncthreads();                       // writes visible before next reads
        }
    }

    // C/D layout: col = lane&15 (=q), row = (lane>>4)*4 + r.
    const int trow0 = row0 + wm * 16 + g * 4;
#pragma unroll
    for (int nt = 0; nt < 3; ++nt) {
        const int c = wn * 48 + nt * 16 + q;
#pragma unroll
        for (int r = 0; r < 4; ++r) {
            const unsigned short v = f2bf(acc[nt][r]);
            const int t = trow0 + r;
            if (c < 64) {
                Q[(size_t)t * HEAD + c] = v;
            } else if (c < 128) {
                K[(size_t)t * HEAD + (c - 64)] = v;
            } else {
                const int bb = t >> 11, tl = t & (SEQ - 1);
                VT[((size_t)bb * HEAD + (c - 128)) * SEQ + tl] = v;
            }
        }
    }
}

// =====================================================================
// Kernel 2: causal flash attention via bf16 MFMA, pipelined + split-KV.
// (unchanged from round 4)
// =====================================================================
__global__ __launch_bounds__(256) void attn_mfma(
    const unsigned short* __restrict__ Q, const unsigned short* __restrict__ K,
    const unsigned short* __restrict__ VT, float* __restrict__ O)
{
    __shared__ unsigned short Ks[2][64][72];   // [buf][kk][d]
    __shared__ unsigned short Vs[2][64][72];   // [buf][d][kk]
    __shared__ unsigned short Ps[64][72];      // [wv*16+q][kk]
    __shared__ float Mo[2][16][68];            // merge: pair-1 O partial
    __shared__ float Mm[2][16], Ml[2][16];     // merge: pair-1 m,l

    const int tid  = threadIdx.x;
    const int l    = tid & 63;
    const int wv   = tid >> 6;               // 0..3
    const int pair = wv >> 1, sub = wv & 1;
    const int g    = l >> 4, q = l & 15;
    const int qt   = 63 - (blockIdx.x >> 3); // largest-work blocks first
    const int b    = blockIdx.x & 7;
    const int qrow0 = qt * 32 + sub * 16;
    const size_t kbase = (size_t)b * SEQ * HEAD;
    const size_t vbase = (size_t)b * HEAD * SEQ;

    short8 bq[2];
#pragma unroll
    for (int dc = 0; dc < 2; ++dc)
        bq[dc] = *(const short8*)&Q[kbase + (size_t)(qrow0 + q) * HEAD + dc * 32 + g * 8];

    floatx4 o[4];
#pragma unroll
    for (int dt = 0; dt < 4; ++dt) o[dt] = (floatx4){0.f, 0.f, 0.f, 0.f};
    float m_run = -INFINITY, l_run = 0.f;

    const int nkt = (qt >> 1) + 1;

    short8 kreg[2], vreg[2];
#pragma unroll
    for (int i = 0; i < 2; ++i) {
        const int c = tid + i * 256, r = c >> 3, k8 = (c & 7) * 8;
        kreg[i] = *(const short8*)&K [kbase + (size_t)r * HEAD + k8];
        vreg[i] = *(const short8*)&VT[vbase + (size_t)r * SEQ  + k8];
    }

    for (int kt = 0; kt < nkt; ++kt) {
        const int bs = kt & 1;
#pragma unroll
        for (int i = 0; i < 2; ++i) {
            const int c = tid + i * 256, r = c >> 3, k8 = (c & 7) * 8;
            *(short8*)&Ks[bs][r][k8] = kreg[i];
            *(short8*)&Vs[bs][r][k8] = vreg[i];
        }
        __syncthreads();

        if (kt + 1 < nkt) {
#pragma unroll
            for (int i = 0; i < 2; ++i) {
                const int c = tid + i * 256, r = c >> 3, k8 = (c & 7) * 8;
                kreg[i] = *(const short8*)&K [kbase + (size_t)((kt + 1) * 64 + r) * HEAD + k8];
                vreg[i] = *(const short8*)&VT[vbase + (size_t)r * SEQ + (kt + 1) * 64 + k8];
            }
        }

        if ((kt & 1) == pair) {
            floatx4 s[4];
#pragma unroll
            for (int t = 0; t < 4; ++t) {
                s[t] = (floatx4){0.f, 0.f, 0.f, 0.f};
#pragma unroll
                for (int dc = 0; dc < 2; ++dc) {
                    const short8 ak = *(const short8*)&Ks[bs][t * 16 + q][dc * 32 + g * 8];
                    s[t] = __builtin_amdgcn_mfma_f32_16x16x32_bf16(ak, bq[dc], s[t], 0, 0, 0);
                }
            }

            float sv[4][4];
            if (kt == nkt - 1) {
#pragma unroll
                for (int t = 0; t < 4; ++t)
#pragma unroll
                    for (int r = 0; r < 4; ++r) {
                        const int kg = kt * 64 + t * 16 + g * 4 + r;
                        sv[t][r] = (kg > qrow0 + q) ? -INFINITY : s[t][r] * 0.125f;
                    }
            } else {
#pragma unroll
                for (int t = 0; t < 4; ++t)
#pragma unroll
                    for (int r = 0; r < 4; ++r) sv[t][r] = s[t][r] * 0.125f;
            }

            float pm = -INFINITY;
#pragma unroll
            for (int t = 0; t < 4; ++t)
#pragma unroll
                for (int r = 0; r < 4; ++r) pm = fmaxf(pm, sv[t][r]);
            pm = fmaxf(pm, __shfl_xor(pm, 16));
            pm = fmaxf(pm, __shfl_xor(pm, 32));
            const float mnew = fmaxf(m_run, pm);
            const float crow = __expf(m_run - mnew);
            float p[4][4];
            float psum = 0.f;
#pragma unroll
            for (int t = 0; t < 4; ++t)
#pragma unroll
                for (int r = 0; r < 4; ++r) {
                    p[t][r] = __expf(sv[t][r] - mnew);
                    psum += p[t][r];
                }
            psum += __shfl_xor(psum, 16);
            psum += __shfl_xor(psum, 32);
            l_run = l_run * crow + psum;
            m_run = mnew;

#pragma unroll
            for (int r = 0; r < 4; ++r) {
                const float cr = __shfl(crow, g * 4 + r);
#pragma unroll
                for (int dt = 0; dt < 4; ++dt) o[dt][r] *= cr;
            }

#pragma unroll
            for (int t = 0; t < 4; ++t) {
                const unsigned int lo = (unsigned)f2bf(p[t][0]) | ((unsigned)f2bf(p[t][1]) << 16);
                const unsigned int hi = (unsigned)f2bf(p[t][2]) | ((unsigned)f2bf(p[t][3]) << 16);
                *(unsigned int*)&Ps[wv * 16 + q][t * 16 + g * 4]     = lo;
                *(unsigned int*)&Ps[wv * 16 + q][t * 16 + g * 4 + 2] = hi;
            }
            asm volatile("s_waitcnt lgkmcnt(0)" ::: "memory");
            __builtin_amdgcn_sched_barrier(0);

#pragma unroll
            for (int kc = 0; kc < 2; ++kc) {
                const short8 pa = *(const short8*)&Ps[wv * 16 + q][kc * 32 + g * 8];
#pragma unroll
                for (int dt = 0; dt < 4; ++dt) {
                    const short8 vb = *(const short8*)&Vs[bs][dt * 16 + q][kc * 32 + g * 8];
                    o[dt] = __builtin_amdgcn_mfma_f32_16x16x32_bf16(pa, vb, o[dt], 0, 0, 0);
                }
            }
        }
    }

    __syncthreads();
    if (pair == 1) {
#pragma unroll
        for (int dt = 0; dt < 4; ++dt)
#pragma unroll
            for (int r = 0; r < 4; ++r)
                Mo[sub][g * 4 + r][dt * 16 + q] = o[dt][r];
        if (g == 0) { Mm[sub][q] = m_run; Ml[sub][q] = l_run; }
    }
    __syncthreads();
    if (pair == 0) {
        const float m1  = Mm[sub][q];
        const float l1v = Ml[sub][q];
        const float mx  = fmaxf(m_run, m1);
        const float c0  = __expf(m_run - mx);
        const float c1  = __expf(m1 - mx);
        const float lm  = l_run * c0 + l1v * c1;
        const size_t obase = (size_t)b * SEQ * HEAD;
#pragma unroll
        for (int r = 0; r < 4; ++r) {
            const float c0r = __shfl(c0, g * 4 + r);
            const float c1r = __shfl(c1, g * 4 + r);
            const float lr  = __shfl(lm, g * 4 + r);
            const float inv = 1.0f / lr;
#pragma unroll
            for (int dt = 0; dt < 4; ++dt) {
                const float val = o[dt][r] * c0r + Mo[sub][g * 4 + r][dt * 16 + q] * c1r;
                O[obase + (size_t)(qrow0 + g * 4 + r) * HEAD + dt * 16 + q] = val * inv;
            }
        }
    }
}

// =====================================================================
extern "C" void kernel_launch(void* const* d_in, const int* in_sizes, int n_in,
                              void* d_out, int out_size, void* d_ws, size_t ws_size,
                              hipStream_t stream)
{
    const float* X  = (const float*)d_in[0];
    const float* Wq = (const float*)d_in[1];
    const float* Wk = (const float*)d_in[2];
    const float* Wv = (const float*)d_in[3];
    float* O = (float*)d_out;

    unsigned short* Qb = (unsigned short*)d_ws;              // [BT][64] bf16
    unsigned short* Kb = Qb + (size_t)BT * HEAD;             // [BT][64]
    unsigned short* Vt = Kb + (size_t)BT * HEAD;             // [B][64][2048]
    unsigned short* WT = Vt + (size_t)BT * HEAD;             // [192][1024]

    wt_prep  <<<dim3(48),  dim3(256), 0, stream>>>(Wq, Wk, Wv, WT);
    qkv_mfma <<<dim3(512), dim3(512), 0, stream>>>(X, WT, Qb, Kb, Vt);
    attn_mfma<<<dim3(512), dim3(256), 0, stream>>>(Qb, Kb, Vt, O);
}

// Round 8
// 172.613 us; speedup vs baseline: 1.1488x; 1.0059x over previous
//
#include <hip/hip_runtime.h>
#include <hip/hip_bf16.h>
#include <math.h>

#define BATCH 8
#define SEQ   2048
#define EMB   1024
#define HEAD  64
#define BT    (BATCH * SEQ)

typedef __attribute__((ext_vector_type(8))) short  short8;
typedef __attribute__((ext_vector_type(4))) short  short4v;
typedef __attribute__((ext_vector_type(4))) float  floatx4;

__device__ __forceinline__ unsigned short f2bf(float x) {
    union { __hip_bfloat16 h; unsigned short u; } cv;
    cv.h = __float2bfloat16(x);   // RNE
    return cv.u;
}

// =====================================================================
// Kernel 0: transpose+convert weights -> WT[192][1024] bf16.
// WT[c][k]: c in [0,64)=Wq col, [64,128)=Wk, [128,192)=Wv.
// =====================================================================
__global__ __launch_bounds__(256) void wt_prep(
    const float* __restrict__ Wq, const float* __restrict__ Wk,
    const float* __restrict__ Wv, unsigned short* __restrict__ WT)
{
    __shared__ float tile[64][65];
    const int w  = blockIdx.x >> 4;        // 0..2
    const int k0 = (blockIdx.x & 15) * 64;
    const float* W = (w == 0) ? Wq : (w == 1) ? Wk : Wv;
    const int tid = threadIdx.x;

    for (int idx = tid; idx < 4096; idx += 256) {
        const int kr = idx >> 6, n = idx & 63;       // coalesced over n
        tile[kr][n] = W[(size_t)(k0 + kr) * HEAD + n];
    }
    __syncthreads();
    const int n  = tid >> 2;
    const int k8 = (tid & 3) * 16;
    unsigned short* dst = WT + (size_t)(w * 64 + n) * EMB + k0 + k8;
    short8 v0, v1;
#pragma unroll
    for (int j = 0; j < 8; ++j) v0[j] = (short)f2bf(tile[k8 + j][n]);
#pragma unroll
    for (int j = 0; j < 8; ++j) v1[j] = (short)f2bf(tile[k8 + 8 + j][n]);
    *(short8*)(dst)     = v0;
    *(short8*)(dst + 8) = v1;
}

// =====================================================================
// Kernel 1: QKV projection, 2-phase LDS GEMM with bf16-in-LDS.
// grid = BT/32 = 512 blocks x 512 thr (8 waves = 2M x 4N).
// Per 64-K chunk: X fp32 -> cvt bf16 at stage -> LDS [32][64] bf16,
// XOR-swizzle byte ^= (row&7)<<4 (both ds_write and ds_read; minimum
// bank aliasing verified for both patterns). Double-buffered.
// Pipeline: X(t+2), W(t+1) issued at iter t; cvt (vmcnt wait) BEFORE
// the barrier; barrier/ds_write/barrier region has no memory waits.
// A-frag: single ds_read_b128 -> MFMA (no cvt on critical path).
// Outputs: Q,K natural [t][64] bf16; V transposed VT[b][64][2048] bf16.
// =====================================================================
__global__ __launch_bounds__(512) void qkv_mfma(
    const float* __restrict__ X, const unsigned short* __restrict__ WT,
    unsigned short* __restrict__ Q, unsigned short* __restrict__ K,
    unsigned short* __restrict__ VT)
{
    __shared__ unsigned short Xs[2][32 * 64];   // bf16, swizzled, 8 KB

    const int tid = threadIdx.x;
    const int l   = tid & 63;
    const int wv  = tid >> 6;              // 0..7
    const int wm  = wv >> 2, wn = wv & 3;  // 2M x 4N
    const int g   = l >> 4,  q  = l & 15;
    const int row0 = blockIdx.x * 32;

    // staging coords: thread loads 16B fp32 (row sr, cols sj*4..+3),
    // writes 8B bf16 at byte (sj*8) ^ ((sr&7)<<4) within the 128B row.
    const int sr = tid >> 4, sj = tid & 15;
    const float* xsrc = X + (size_t)(row0 + sr) * EMB + sj * 4;
    const int soff = sr * 128 + ((sj * 8) ^ ((sr & 7) << 4));
    char* const sdst0 = (char*)&Xs[0][0] + soff;
    char* const sdst1 = (char*)&Xs[1][0] + soff;

    // A-frag read coords: row rr, byte (kc*64 + g*16) ^ ((rr&7)<<4)
    const int rr  = wm * 16 + q;
    const int rsw = (rr & 7) << 4;
    const char* const rbase0 = (const char*)&Xs[0][0] + rr * 128;
    const char* const rbase1 = (const char*)&Xs[1][0] + rr * 128;

    const unsigned short* wbase = WT + (size_t)(wn * 48 + q) * EMB + g * 8;

    floatx4 acc[3];
#pragma unroll
    for (int nt = 0; nt < 3; ++nt) acc[nt] = (floatx4){0.f, 0.f, 0.f, 0.f};

    float4 xreg[2];
    short8 wreg[2][6];

    // prologue: issue X(0), X(1), W(0); cvt+stage chunk 0 into buf0
    xreg[0] = *(const float4*)(xsrc);
    xreg[1] = *(const float4*)(xsrc + 64);
#pragma unroll
    for (int nt = 0; nt < 3; ++nt)
#pragma unroll
        for (int kc = 0; kc < 2; ++kc)
            wreg[0][nt * 2 + kc] = *(const short8*)(wbase + (size_t)nt * 16 * EMB + kc * 32);
    {
        const float4 xc = xreg[0];
        short4v b;
        b[0] = (short)f2bf(xc.x); b[1] = (short)f2bf(xc.y);
        b[2] = (short)f2bf(xc.z); b[3] = (short)f2bf(xc.w);
        *(short4v*)sdst0 = b;
    }

#pragma unroll
    for (int t = 0; t < 16; ++t) {
        // issue loads two / one chunk ahead (slots free by schedule)
        if (t + 2 < 16)
            xreg[t & 1] = *(const float4*)(xsrc + (t + 2) * 64);
        if (t + 1 < 16) {
#pragma unroll
            for (int nt = 0; nt < 3; ++nt)
#pragma unroll
                for (int kc = 0; kc < 2; ++kc)
                    wreg[(t + 1) & 1][nt * 2 + kc] =
                        *(const short8*)(wbase + (size_t)nt * 16 * EMB + (t + 1) * 64 + kc * 32);
            // cvt chunk t+1 (vmcnt wait lands here, pre-barrier)
            const float4 xc = xreg[(t + 1) & 1];
            short4v b;
            b[0] = (short)f2bf(xc.x); b[1] = (short)f2bf(xc.y);
            b[2] = (short)f2bf(xc.z); b[3] = (short)f2bf(xc.w);
            __syncthreads();                       // readers of buf[(t+1)&1] done
            *(short4v*)(((t + 1) & 1) ? sdst1 : sdst0) = b;
            __syncthreads();                       // staged chunk visible
        }
        // compute chunk t from buf[t&1]
#pragma unroll
        for (int kc = 0; kc < 2; ++kc) {
            const short8 a = *(const short8*)(((t & 1) ? rbase1 : rbase0)
                                              + ((kc * 64 + g * 16) ^ rsw));
#pragma unroll
            for (int nt = 0; nt < 3; ++nt)
                acc[nt] = __builtin_amdgcn_mfma_f32_16x16x32_bf16(
                    a, wreg[t & 1][nt * 2 + kc], acc[nt], 0, 0, 0);
        }
    }

    // C/D layout: col = lane&15 (=q), row = (lane>>4)*4 + r.
    const int trow0 = row0 + wm * 16 + g * 4;
#pragma unroll
    for (int nt = 0; nt < 3; ++nt) {
        const int c = wn * 48 + nt * 16 + q;
#pragma unroll
        for (int r = 0; r < 4; ++r) {
            const unsigned short v = f2bf(acc[nt][r]);
            const int t = trow0 + r;
            if (c < 64) {
                Q[(size_t)t * HEAD + c] = v;
            } else if (c < 128) {
                K[(size_t)t * HEAD + (c - 64)] = v;
            } else {
                const int bb = t >> 11, tl = t & (SEQ - 1);
                VT[((size_t)bb * HEAD + (c - 128)) * SEQ + tl] = v;
            }
        }
    }
}

// =====================================================================
// Kernel 2: causal flash attention via bf16 MFMA, pipelined + split-KV.
// (unchanged from round 5)
// =====================================================================
__global__ __launch_bounds__(256) void attn_mfma(
    const unsigned short* __restrict__ Q, const unsigned short* __restrict__ K,
    const unsigned short* __restrict__ VT, float* __restrict__ O)
{
    __shared__ unsigned short Ks[2][64][72];   // [buf][kk][d]
    __shared__ unsigned short Vs[2][64][72];   // [buf][d][kk]
    __shared__ unsigned short Ps[64][72];      // [wv*16+q][kk]
    __shared__ float Mo[2][16][68];            // merge: pair-1 O partial
    __shared__ float Mm[2][16], Ml[2][16];     // merge: pair-1 m,l

    const int tid  = threadIdx.x;
    const int l    = tid & 63;
    const int wv   = tid >> 6;               // 0..3
    const int pair = wv >> 1, sub = wv & 1;
    const int g    = l >> 4, q = l & 15;
    const int qt   = 63 - (blockIdx.x >> 3); // largest-work blocks first
    const int b    = blockIdx.x & 7;
    const int qrow0 = qt * 32 + sub * 16;
    const size_t kbase = (size_t)b * SEQ * HEAD;
    const size_t vbase = (size_t)b * HEAD * SEQ;

    short8 bq[2];
#pragma unroll
    for (int dc = 0; dc < 2; ++dc)
        bq[dc] = *(const short8*)&Q[kbase + (size_t)(qrow0 + q) * HEAD + dc * 32 + g * 8];

    floatx4 o[4];
#pragma unroll
    for (int dt = 0; dt < 4; ++dt) o[dt] = (floatx4){0.f, 0.f, 0.f, 0.f};
    float m_run = -INFINITY, l_run = 0.f;

    const int nkt = (qt >> 1) + 1;

    short8 kreg[2], vreg[2];
#pragma unroll
    for (int i = 0; i < 2; ++i) {
        const int c = tid + i * 256, r = c >> 3, k8 = (c & 7) * 8;
        kreg[i] = *(const short8*)&K [kbase + (size_t)r * HEAD + k8];
        vreg[i] = *(const short8*)&VT[vbase + (size_t)r * SEQ  + k8];
    }

    for (int kt = 0; kt < nkt; ++kt) {
        const int bs = kt & 1;
#pragma unroll
        for (int i = 0; i < 2; ++i) {
            const int c = tid + i * 256, r = c >> 3, k8 = (c & 7) * 8;
            *(short8*)&Ks[bs][r][k8] = kreg[i];
            *(short8*)&Vs[bs][r][k8] = vreg[i];
        }
        __syncthreads();

        if (kt + 1 < nkt) {
#pragma unroll
            for (int i = 0; i < 2; ++i) {
                const int c = tid + i * 256, r = c >> 3, k8 = (c & 7) * 8;
                kreg[i] = *(const short8*)&K [kbase + (size_t)((kt + 1) * 64 + r) * HEAD + k8];
                vreg[i] = *(const short8*)&VT[vbase + (size_t)r * SEQ + (kt + 1) * 64 + k8];
            }
        }

        if ((kt & 1) == pair) {
            floatx4 s[4];
#pragma unroll
            for (int t = 0; t < 4; ++t) {
                s[t] = (floatx4){0.f, 0.f, 0.f, 0.f};
#pragma unroll
                for (int dc = 0; dc < 2; ++dc) {
                    const short8 ak = *(const short8*)&Ks[bs][t * 16 + q][dc * 32 + g * 8];
                    s[t] = __builtin_amdgcn_mfma_f32_16x16x32_bf16(ak, bq[dc], s[t], 0, 0, 0);
                }
            }

            float sv[4][4];
            if (kt == nkt - 1) {
#pragma unroll
                for (int t = 0; t < 4; ++t)
#pragma unroll
                    for (int r = 0; r < 4; ++r) {
                        const int kg = kt * 64 + t * 16 + g * 4 + r;
                        sv[t][r] = (kg > qrow0 + q) ? -INFINITY : s[t][r] * 0.125f;
                    }
            } else {
#pragma unroll
                for (int t = 0; t < 4; ++t)
#pragma unroll
                    for (int r = 0; r < 4; ++r) sv[t][r] = s[t][r] * 0.125f;
            }

            float pm = -INFINITY;
#pragma unroll
            for (int t = 0; t < 4; ++t)
#pragma unroll
                for (int r = 0; r < 4; ++r) pm = fmaxf(pm, sv[t][r]);
            pm = fmaxf(pm, __shfl_xor(pm, 16));
            pm = fmaxf(pm, __shfl_xor(pm, 32));
            const float mnew = fmaxf(m_run, pm);
            const float crow = __expf(m_run - mnew);
            float p[4][4];
            float psum = 0.f;
#pragma unroll
            for (int t = 0; t < 4; ++t)
#pragma unroll
                for (int r = 0; r < 4; ++r) {
                    p[t][r] = __expf(sv[t][r] - mnew);
                    psum += p[t][r];
                }
            psum += __shfl_xor(psum, 16);
            psum += __shfl_xor(psum, 32);
            l_run = l_run * crow + psum;
            m_run = mnew;

#pragma unroll
            for (int r = 0; r < 4; ++r) {
                const float cr = __shfl(crow, g * 4 + r);
#pragma unroll
                for (int dt = 0; dt < 4; ++dt) o[dt][r] *= cr;
            }

#pragma unroll
            for (int t = 0; t < 4; ++t) {
                const unsigned int lo = (unsigned)f2bf(p[t][0]) | ((unsigned)f2bf(p[t][1]) << 16);
                const unsigned int hi = (unsigned)f2bf(p[t][2]) | ((unsigned)f2bf(p[t][3]) << 16);
                *(unsigned int*)&Ps[wv * 16 + q][t * 16 + g * 4]     = lo;
                *(unsigned int*)&Ps[wv * 16 + q][t * 16 + g * 4 + 2] = hi;
            }
            asm volatile("s_waitcnt lgkmcnt(0)" ::: "memory");
            __builtin_amdgcn_sched_barrier(0);

#pragma unroll
            for (int kc = 0; kc < 2; ++kc) {
                const short8 pa = *(const short8*)&Ps[wv * 16 + q][kc * 32 + g * 8];
#pragma unroll
                for (int dt = 0; dt < 4; ++dt) {
                    const short8 vb = *(const short8*)&Vs[bs][dt * 16 + q][kc * 32 + g * 8];
                    o[dt] = __builtin_amdgcn_mfma_f32_16x16x32_bf16(pa, vb, o[dt], 0, 0, 0);
                }
            }
        }
    }

    __syncthreads();
    if (pair == 1) {
#pragma unroll
        for (int dt = 0; dt < 4; ++dt)
#pragma unroll
            for (int r = 0; r < 4; ++r)
                Mo[sub][g * 4 + r][dt * 16 + q] = o[dt][r];
        if (g == 0) { Mm[sub][q] = m_run; Ml[sub][q] = l_run; }
    }
    __syncthreads();
    if (pair == 0) {
        const float m1  = Mm[sub][q];
        const float l1v = Ml[sub][q];
        const float mx  = fmaxf(m_run, m1);
        const float c0  = __expf(m_run - mx);
        const float c1  = __expf(m1 - mx);
        const float lm  = l_run * c0 + l1v * c1;
        const size_t obase = (size_t)b * SEQ * HEAD;
#pragma unroll
        for (int r = 0; r < 4; ++r) {
            const float c0r = __shfl(c0, g * 4 + r);
            const float c1r = __shfl(c1, g * 4 + r);
            const float lr  = __shfl(lm, g * 4 + r);
            const float inv = 1.0f / lr;
#pragma unroll
            for (int dt = 0; dt < 4; ++dt) {
                const float val = o[dt][r] * c0r + Mo[sub][g * 4 + r][dt * 16 + q] * c1r;
                O[obase + (size_t)(qrow0 + g * 4 + r) * HEAD + dt * 16 + q] = val * inv;
            }
        }
    }
}

// =====================================================================
extern "C" void kernel_launch(void* const* d_in, const int* in_sizes, int n_in,
                              void* d_out, int out_size, void* d_ws, size_t ws_size,
                              hipStream_t stream)
{
    const float* X  = (const float*)d_in[0];
    const float* Wq = (const float*)d_in[1];
    const float* Wk = (const float*)d_in[2];
    const float* Wv = (const float*)d_in[3];
    float* O = (float*)d_out;

    unsigned short* Qb = (unsigned short*)d_ws;              // [BT][64] bf16
    unsigned short* Kb = Qb + (size_t)BT * HEAD;             // [BT][64]
    unsigned short* Vt = Kb + (size_t)BT * HEAD;             // [B][64][2048]
    unsigned short* WT = Vt + (size_t)BT * HEAD;             // [192][1024]

    wt_prep  <<<dim3(48),  dim3(256), 0, stream>>>(Wq, Wk, Wv, WT);
    qkv_mfma <<<dim3(512), dim3(512), 0, stream>>>(X, WT, Qb, Kb, Vt);
    attn_mfma<<<dim3(512), dim3(256), 0, stream>>>(Qb, Kb, Vt, O);
}

// Round 9
// 171.309 us; speedup vs baseline: 1.1575x; 1.0076x over previous
//
#include <hip/hip_runtime.h>
#include <hip/hip_bf16.h>
#include <math.h>

#define BATCH 8
#define SEQ   2048
#define EMB   1024
#define HEAD  64
#define BT    (BATCH * SEQ)

typedef __attribute__((ext_vector_type(8))) short  short8;
typedef __attribute__((ext_vector_type(4))) short  short4v;
typedef __attribute__((ext_vector_type(4))) float  floatx4;

__device__ __forceinline__ unsigned short f2bf(float x) {
    union { __hip_bfloat16 h; unsigned short u; } cv;
    cv.h = __float2bfloat16(x);   // RNE
    return cv.u;
}

// Barrier that does NOT drain vmcnt (unlike __syncthreads, which emits
// s_waitcnt vmcnt(0) lgkmcnt(0) and kills global prefetch). LDS ordering
// is preserved: own ds ops retired (lgkmcnt(0)) before signaling.
__device__ __forceinline__ void block_sync_lds() {
    asm volatile("s_waitcnt lgkmcnt(0)" ::: "memory");
    __builtin_amdgcn_s_barrier();
}

// =====================================================================
// Kernel 0: transpose+convert weights -> WT[192][1024] bf16.
// WT[c][k]: c in [0,64)=Wq col, [64,128)=Wk, [128,192)=Wv.
// =====================================================================
__global__ __launch_bounds__(256) void wt_prep(
    const float* __restrict__ Wq, const float* __restrict__ Wk,
    const float* __restrict__ Wv, unsigned short* __restrict__ WT)
{
    __shared__ float tile[64][65];
    const int w  = blockIdx.x >> 4;        // 0..2
    const int k0 = (blockIdx.x & 15) * 64;
    const float* W = (w == 0) ? Wq : (w == 1) ? Wk : Wv;
    const int tid = threadIdx.x;

    for (int idx = tid; idx < 4096; idx += 256) {
        const int kr = idx >> 6, n = idx & 63;       // coalesced over n
        tile[kr][n] = W[(size_t)(k0 + kr) * HEAD + n];
    }
    __syncthreads();
    const int n  = tid >> 2;
    const int k8 = (tid & 3) * 16;
    unsigned short* dst = WT + (size_t)(w * 64 + n) * EMB + k0 + k8;
    short8 v0, v1;
#pragma unroll
    for (int j = 0; j < 8; ++j) v0[j] = (short)f2bf(tile[k8 + j][n]);
#pragma unroll
    for (int j = 0; j < 8; ++j) v1[j] = (short)f2bf(tile[k8 + 8 + j][n]);
    *(short8*)(dst)     = v0;
    *(short8*)(dst + 8) = v1;
}

// =====================================================================
// Kernel 1: QKV projection, 2-phase LDS GEMM with bf16-in-LDS.
// grid = BT/32 = 512 blocks x 512 thr (8 waves = 2M x 4N).
// Identical to round 8 EXCEPT: in-loop barriers are raw s_barrier with
// lgkmcnt(0) only -> X(t+2)/W(t+1) prefetches stay in flight across
// barriers; their waits are counted reg-dep vmcnt at use (T3/T4).
// =====================================================================
__global__ __launch_bounds__(512) void qkv_mfma(
    const float* __restrict__ X, const unsigned short* __restrict__ WT,
    unsigned short* __restrict__ Q, unsigned short* __restrict__ K,
    unsigned short* __restrict__ VT)
{
    __shared__ unsigned short Xs[2][32 * 64];   // bf16, swizzled, 8 KB

    const int tid = threadIdx.x;
    const int l   = tid & 63;
    const int wv  = tid >> 6;              // 0..7
    const int wm  = wv >> 2, wn = wv & 3;  // 2M x 4N
    const int g   = l >> 4,  q  = l & 15;
    const int row0 = blockIdx.x * 32;

    // staging coords: thread loads 16B fp32 (row sr, cols sj*4..+3),
    // writes 8B bf16 at byte (sj*8) ^ ((sr&7)<<4) within the 128B row.
    const int sr = tid >> 4, sj = tid & 15;
    const float* xsrc = X + (size_t)(row0 + sr) * EMB + sj * 4;
    const int soff = sr * 128 + ((sj * 8) ^ ((sr & 7) << 4));
    char* const sdst0 = (char*)&Xs[0][0] + soff;
    char* const sdst1 = (char*)&Xs[1][0] + soff;

    // A-frag read coords: row rr, byte (kc*64 + g*16) ^ ((rr&7)<<4)
    const int rr  = wm * 16 + q;
    const int rsw = (rr & 7) << 4;
    const char* const rbase0 = (const char*)&Xs[0][0] + rr * 128;
    const char* const rbase1 = (const char*)&Xs[1][0] + rr * 128;

    const unsigned short* wbase = WT + (size_t)(wn * 48 + q) * EMB + g * 8;

    floatx4 acc[3];
#pragma unroll
    for (int nt = 0; nt < 3; ++nt) acc[nt] = (floatx4){0.f, 0.f, 0.f, 0.f};

    float4 xreg[2];
    short8 wreg[2][6];

    // prologue: issue X(0), X(1), W(0); cvt+stage chunk 0 into buf0
    xreg[0] = *(const float4*)(xsrc);
    xreg[1] = *(const float4*)(xsrc + 64);
#pragma unroll
    for (int nt = 0; nt < 3; ++nt)
#pragma unroll
        for (int kc = 0; kc < 2; ++kc)
            wreg[0][nt * 2 + kc] = *(const short8*)(wbase + (size_t)nt * 16 * EMB + kc * 32);
    {
        const float4 xc = xreg[0];
        short4v b;
        b[0] = (short)f2bf(xc.x); b[1] = (short)f2bf(xc.y);
        b[2] = (short)f2bf(xc.z); b[3] = (short)f2bf(xc.w);
        *(short4v*)sdst0 = b;
    }

#pragma unroll
    for (int t = 0; t < 16; ++t) {
        // issue loads two / one chunk ahead (stay in flight across barriers)
        if (t + 2 < 16)
            xreg[t & 1] = *(const float4*)(xsrc + (t + 2) * 64);
        if (t + 1 < 16) {
#pragma unroll
            for (int nt = 0; nt < 3; ++nt)
#pragma unroll
                for (int kc = 0; kc < 2; ++kc)
                    wreg[(t + 1) & 1][nt * 2 + kc] =
                        *(const short8*)(wbase + (size_t)nt * 16 * EMB + (t + 1) * 64 + kc * 32);
            // cvt chunk t+1 (counted vmcnt wait on X(t+1) only)
            const float4 xc = xreg[(t + 1) & 1];
            short4v b;
            b[0] = (short)f2bf(xc.x); b[1] = (short)f2bf(xc.y);
            b[2] = (short)f2bf(xc.z); b[3] = (short)f2bf(xc.w);
            block_sync_lds();                      // readers of buf[(t+1)&1] done
            *(short4v*)(((t + 1) & 1) ? sdst1 : sdst0) = b;
            block_sync_lds();                      // staged chunk visible
        }
        // compute chunk t from buf[t&1]
#pragma unroll
        for (int kc = 0; kc < 2; ++kc) {
            const short8 a = *(const short8*)(((t & 1) ? rbase1 : rbase0)
                                              + ((kc * 64 + g * 16) ^ rsw));
#pragma unroll
            for (int nt = 0; nt < 3; ++nt)
                acc[nt] = __builtin_amdgcn_mfma_f32_16x16x32_bf16(
                    a, wreg[t & 1][nt * 2 + kc], acc[nt], 0, 0, 0);
        }
    }

    // C/D layout: col = lane&15 (=q), row = (lane>>4)*4 + r.
    const int trow0 = row0 + wm * 16 + g * 4;
#pragma unroll
    for (int nt = 0; nt < 3; ++nt) {
        const int c = wn * 48 + nt * 16 + q;
#pragma unroll
        for (int r = 0; r < 4; ++r) {
            const unsigned short v = f2bf(acc[nt][r]);
            const int t = trow0 + r;
            if (c < 64) {
                Q[(size_t)t * HEAD + c] = v;
            } else if (c < 128) {
                K[(size_t)t * HEAD + (c - 64)] = v;
            } else {
                const int bb = t >> 11, tl = t & (SEQ - 1);
                VT[((size_t)bb * HEAD + (c - 128)) * SEQ + tl] = v;
            }
        }
    }
}

// =====================================================================
// Kernel 2: causal flash attention via bf16 MFMA, pipelined + split-KV.
// Identical to round 8 EXCEPT the per-tile barrier is non-vmcnt-draining
// -> K/V prefetch for kt+1 survives the barrier, waits counted at the
// ds_write next iteration.
// =====================================================================
__global__ __launch_bounds__(256) void attn_mfma(
    const unsigned short* __restrict__ Q, const unsigned short* __restrict__ K,
    const unsigned short* __restrict__ VT, float* __restrict__ O)
{
    __shared__ unsigned short Ks[2][64][72];   // [buf][kk][d]
    __shared__ unsigned short Vs[2][64][72];   // [buf][d][kk]
    __shared__ unsigned short Ps[64][72];      // [wv*16+q][kk]
    __shared__ float Mo[2][16][68];            // merge: pair-1 O partial
    __shared__ float Mm[2][16], Ml[2][16];     // merge: pair-1 m,l

    const int tid  = threadIdx.x;
    const int l    = tid & 63;
    const int wv   = tid >> 6;               // 0..3
    const int pair = wv >> 1, sub = wv & 1;
    const int g    = l >> 4, q = l & 15;
    const int qt   = 63 - (blockIdx.x >> 3); // largest-work blocks first
    const int b    = blockIdx.x & 7;
    const int qrow0 = qt * 32 + sub * 16;
    const size_t kbase = (size_t)b * SEQ * HEAD;
    const size_t vbase = (size_t)b * HEAD * SEQ;

    short8 bq[2];
#pragma unroll
    for (int dc = 0; dc < 2; ++dc)
        bq[dc] = *(const short8*)&Q[kbase + (size_t)(qrow0 + q) * HEAD + dc * 32 + g * 8];

    floatx4 o[4];
#pragma unroll
    for (int dt = 0; dt < 4; ++dt) o[dt] = (floatx4){0.f, 0.f, 0.f, 0.f};
    float m_run = -INFINITY, l_run = 0.f;

    const int nkt = (qt >> 1) + 1;

    short8 kreg[2], vreg[2];
#pragma unroll
    for (int i = 0; i < 2; ++i) {
        const int c = tid + i * 256, r = c >> 3, k8 = (c & 7) * 8;
        kreg[i] = *(const short8*)&K [kbase + (size_t)r * HEAD + k8];
        vreg[i] = *(const short8*)&VT[vbase + (size_t)r * SEQ  + k8];
    }

    for (int kt = 0; kt < nkt; ++kt) {
        const int bs = kt & 1;
        // stage prefetched regs -> LDS (counted vmcnt wait via reg dep)
#pragma unroll
        for (int i = 0; i < 2; ++i) {
            const int c = tid + i * 256, r = c >> 3, k8 = (c & 7) * 8;
            *(short8*)&Ks[bs][r][k8] = kreg[i];
            *(short8*)&Vs[bs][r][k8] = vreg[i];
        }
        block_sync_lds();

        // issue next-tile loads; stay in flight across next barrier
        if (kt + 1 < nkt) {
#pragma unroll
            for (int i = 0; i < 2; ++i) {
                const int c = tid + i * 256, r = c >> 3, k8 = (c & 7) * 8;
                kreg[i] = *(const short8*)&K [kbase + (size_t)((kt + 1) * 64 + r) * HEAD + k8];
                vreg[i] = *(const short8*)&VT[vbase + (size_t)r * SEQ + (kt + 1) * 64 + k8];
            }
        }

        if ((kt & 1) == pair) {
            floatx4 s[4];
#pragma unroll
            for (int t = 0; t < 4; ++t) {
                s[t] = (floatx4){0.f, 0.f, 0.f, 0.f};
#pragma unroll
                for (int dc = 0; dc < 2; ++dc) {
                    const short8 ak = *(const short8*)&Ks[bs][t * 16 + q][dc * 32 + g * 8];
                    s[t] = __builtin_amdgcn_mfma_f32_16x16x32_bf16(ak, bq[dc], s[t], 0, 0, 0);
                }
            }

            float sv[4][4];
            if (kt == nkt - 1) {
#pragma unroll
                for (int t = 0; t < 4; ++t)
#pragma unroll
                    for (int r = 0; r < 4; ++r) {
                        const int kg = kt * 64 + t * 16 + g * 4 + r;
                        sv[t][r] = (kg > qrow0 + q) ? -INFINITY : s[t][r] * 0.125f;
                    }
            } else {
#pragma unroll
                for (int t = 0; t < 4; ++t)
#pragma unroll
                    for (int r = 0; r < 4; ++r) sv[t][r] = s[t][r] * 0.125f;
            }

            float pm = -INFINITY;
#pragma unroll
            for (int t = 0; t < 4; ++t)
#pragma unroll
                for (int r = 0; r < 4; ++r) pm = fmaxf(pm, sv[t][r]);
            pm = fmaxf(pm, __shfl_xor(pm, 16));
            pm = fmaxf(pm, __shfl_xor(pm, 32));
            const float mnew = fmaxf(m_run, pm);
            const float crow = __expf(m_run - mnew);
            float p[4][4];
            float psum = 0.f;
#pragma unroll
            for (int t = 0; t < 4; ++t)
#pragma unroll
                for (int r = 0; r < 4; ++r) {
                    p[t][r] = __expf(sv[t][r] - mnew);
                    psum += p[t][r];
                }
            psum += __shfl_xor(psum, 16);
            psum += __shfl_xor(psum, 32);
            l_run = l_run * crow + psum;
            m_run = mnew;

#pragma unroll
            for (int r = 0; r < 4; ++r) {
                const float cr = __shfl(crow, g * 4 + r);
#pragma unroll
                for (int dt = 0; dt < 4; ++dt) o[dt][r] *= cr;
            }

#pragma unroll
            for (int t = 0; t < 4; ++t) {
                const unsigned int lo = (unsigned)f2bf(p[t][0]) | ((unsigned)f2bf(p[t][1]) << 16);
                const unsigned int hi = (unsigned)f2bf(p[t][2]) | ((unsigned)f2bf(p[t][3]) << 16);
                *(unsigned int*)&Ps[wv * 16 + q][t * 16 + g * 4]     = lo;
                *(unsigned int*)&Ps[wv * 16 + q][t * 16 + g * 4 + 2] = hi;
            }
            asm volatile("s_waitcnt lgkmcnt(0)" ::: "memory");
            __builtin_amdgcn_sched_barrier(0);

#pragma unroll
            for (int kc = 0; kc < 2; ++kc) {
                const short8 pa = *(const short8*)&Ps[wv * 16 + q][kc * 32 + g * 8];
#pragma unroll
                for (int dt = 0; dt < 4; ++dt) {
                    const short8 vb = *(const short8*)&Vs[bs][dt * 16 + q][kc * 32 + g * 8];
                    o[dt] = __builtin_amdgcn_mfma_f32_16x16x32_bf16(pa, vb, o[dt], 0, 0, 0);
                }
            }
        }
    }

    __syncthreads();
    if (pair == 1) {
#pragma unroll
        for (int dt = 0; dt < 4; ++dt)
#pragma unroll
            for (int r = 0; r < 4; ++r)
                Mo[sub][g * 4 + r][dt * 16 + q] = o[dt][r];
        if (g == 0) { Mm[sub][q] = m_run; Ml[sub][q] = l_run; }
    }
    __syncthreads();
    if (pair == 0) {
        const float m1  = Mm[sub][q];
        const float l1v = Ml[sub][q];
        const float mx  = fmaxf(m_run, m1);
        const float c0  = __expf(m_run - mx);
        const float c1  = __expf(m1 - mx);
        const float lm  = l_run * c0 + l1v * c1;
        const size_t obase = (size_t)b * SEQ * HEAD;
#pragma unroll
        for (int r = 0; r < 4; ++r) {
            const float c0r = __shfl(c0, g * 4 + r);
            const float c1r = __shfl(c1, g * 4 + r);
            const float lr  = __shfl(lm, g * 4 + r);
            const float inv = 1.0f / lr;
#pragma unroll
            for (int dt = 0; dt < 4; ++dt) {
                const float val = o[dt][r] * c0r + Mo[sub][g * 4 + r][dt * 16 + q] * c1r;
                O[obase + (size_t)(qrow0 + g * 4 + r) * HEAD + dt * 16 + q] = val * inv;
            }
        }
    }
}

// =====================================================================
extern "C" void kernel_launch(void* const* d_in, const int* in_sizes, int n_in,
                              void* d_out, int out_size, void* d_ws, size_t ws_size,
                              hipStream_t stream)
{
    const float* X  = (const float*)d_in[0];
    const float* Wq = (const float*)d_in[1];
    const float* Wk = (const float*)d_in[2];
    const float* Wv = (const float*)d_in[3];
    float* O = (float*)d_out;

    unsigned short* Qb = (unsigned short*)d_ws;              // [BT][64] bf16
    unsigned short* Kb = Qb + (size_t)BT * HEAD;             // [BT][64]
    unsigned short* Vt = Kb + (size_t)BT * HEAD;             // [B][64][2048]
    unsigned short* WT = Vt + (size_t)BT * HEAD;             // [192][1024]

    wt_prep  <<<dim3(48),  dim3(256), 0, stream>>>(Wq, Wk, Wv, WT);
    qkv_mfma <<<dim3(512), dim3(512), 0, stream>>>(X, WT, Qb, Kb, Vt);
    attn_mfma<<<dim3(512), dim3(256), 0, stream>>>(Qb, Kb, Vt, O);
}